// Round 10
// baseline (269.203 us; speedup 1.0000x reference)
//
#include <hip/hip_runtime.h>
#include <hip/hip_bf16.h>
#include <float.h>
#include <math.h>

// Problem constants (from reference)
#define NN 20000
#define EE 320000
#define IN_DIM 128
#define DEG_CAP 64   // bucket stride; Poisson(16) => P(max deg > 64) ~ 1e-13

typedef __attribute__((ext_vector_type(4))) float f32x4;
typedef _Float16 f16;
typedef __attribute__((ext_vector_type(2))) _Float16 f16x2;
typedef __attribute__((ext_vector_type(4))) _Float16 f16x4;
typedef __attribute__((ext_vector_type(8))) _Float16 f16x8;

typedef const unsigned int __attribute__((address_space(1)))* gas_u32p;
typedef unsigned int __attribute__((address_space(3)))* las_u32p;

#define LOG2E 1.4426950408889634f

// DPP lane-group sum stage: v += dpp(v, CTRL). Pure VALU (no LDS/bpermute).
template <int CTRL>
__device__ __forceinline__ float dpp_add(float v) {
    int x = __builtin_amdgcn_update_dpp(0, __builtin_bit_cast(int, v), CTRL, 0xF, 0xF, false);
    return v + __builtin_bit_cast(float, x);
}
// Complete sum over aligned lane group of GSZ (8: half-mirror+xor1+xor2; 4: xor1+xor2).
template <int GSZ>
__device__ __forceinline__ float group_sum(float v) {
    if constexpr (GSZ == 8) v = dpp_add<0x141>(v);   // row_half_mirror: i <-> 7-i
    v = dpp_add<0xB1>(v);                             // quad_perm [1,0,3,2]: xor 1
    v = dpp_add<0x4E>(v);                             // quad_perm [2,3,0,1]: xor 2
    return v;
}

// ---------- weight prep element: concat + transpose, single f16 ----------
__device__ __forceinline__ void prep_elem(const float* __restrict__ Wa, const float* __restrict__ ba, int na,
                                          const float* __restrict__ Wb, const float* __restrict__ bb, int nb,
                                          const float* __restrict__ Wc, const float* __restrict__ bc, int nc,
                                          int K, f16* __restrict__ Wt, float* __restrict__ bias_cat, int idx) {
    int n = idx / K;
    int k = idx - n * K;
    const float* W; const float* b; int nl; int ncols;
    if (n < na) { W = Wa; b = ba; nl = n; ncols = na; }
    else if (n < na + nb) { W = Wb; b = bb; nl = n - na; ncols = nb; }
    else { W = Wc; b = bc; nl = n - na - nb; ncols = nc; }
    Wt[(size_t)n * K + k] = (f16)W[(size_t)k * ncols + nl];
    if (k == 0) bias_cat[n] = b[nl];
}

// ---------- one launch: weight preps + x -> f16 (scatter folded into gemm0) ----------
#define SEG0 (512 * 128)
#define SEG1 (512 * 256)
#define SEG2 (576 * 256)
#define SEG3 (NN * IN_DIM / 4)
__global__ void prep_all(const float* __restrict__ W0s, const float* __restrict__ b0s,
                         const float* __restrict__ W0d, const float* __restrict__ b0d,
                         const float* __restrict__ W1s, const float* __restrict__ b1s,
                         const float* __restrict__ W1d, const float* __restrict__ b1d,
                         const float* __restrict__ W2s, const float* __restrict__ b2s,
                         const float* __restrict__ W2d, const float* __restrict__ b2d,
                         const float* __restrict__ Wr2, const float* __restrict__ br2,
                         const float* __restrict__ x,
                         f16* __restrict__ Wt0, float* __restrict__ bias0,
                         f16* __restrict__ Wt1, float* __restrict__ bias1,
                         f16* __restrict__ Wt2, float* __restrict__ bias2,
                         f16* __restrict__ A) {
    int idx = blockIdx.x * 256 + threadIdx.x;
    if (idx < SEG0) {
        prep_elem(W0s, b0s, 256, W0d, b0d, 256, nullptr, nullptr, 0, 128, Wt0, bias0, idx);
    } else if ((idx -= SEG0) < SEG1) {
        prep_elem(W1s, b1s, 256, W1d, b1d, 256, nullptr, nullptr, 0, 256, Wt1, bias1, idx);
    } else if ((idx -= SEG1) < SEG2) {
        prep_elem(W2s, b2s, 192, W2d, b2d, 192, Wr2, br2, 192, 256, Wt2, bias2, idx);
    } else if ((idx -= SEG2) < SEG3) {
        float4 v = ((const float4*)x)[idx];
        f16x4 o = {(f16)v.x, (f16)v.y, (f16)v.z, (f16)v.w};
        ((f16x4*)A)[idx] = o;
    }
}

// ---------- MFMA GEMM, BM=128, K compile-time, A-slice in registers ----------
// Scatter blocks FIRST (bid < SB): their atomic/eviction latency overlaps under the
// following GEMM blocks instead of trailing the dispatch. B via global_load_lds;
// K-loop pure ds_read+MFMA; Cs aliases Bs after the K-loop.
template <int K>
__global__ __launch_bounds__(256) void gemm_mfma_f16(
        const f16* __restrict__ A, const f16* __restrict__ Wt,
        const float* __restrict__ bias,
        f16* __restrict__ F0, f16* __restrict__ F1, float* __restrict__ F2,
        int b1, int b2, int M, int S, int gx, int gy,
        int SB, const int* __restrict__ esrc, const int* __restrict__ edst,
        unsigned int* __restrict__ cursor, int* __restrict__ csr_dst, int E) {
    constexpr int K32 = K / 32;
    constexpr int BSN = (64 * K > 4 * 32 * 66) ? 64 * K : 4 * 32 * 66;
    __shared__ f16 Bs[BSN];          // K=256: 32KB; K=128: 16.9KB

    if (blockIdx.x < (unsigned)SB) {
        // ---- CSR bucket scatter segment (runs FIRST; overlaps the GEMM) ----
        int e = blockIdx.x * 256 + threadIdx.x;
        if (e < E) {
            int d = edst[e];
            unsigned pos = atomicAdd(&cursor[d], 1u);
            if (pos < DEG_CAP) csr_dst[(unsigned)d * DEG_CAP + pos] = esrc[e];
        }
        return;
    }
    const int bid = blockIdx.x - SB;

    const int p = bid & 7;          // XCD slot
    const int q = bid >> 3;
    const int bn_i = q % gx;
    const int bm_i = (q / gx) * 8 + p;
    if (bm_i >= gy) return;
    const int bm = bm_i * 128;
    const int bn = bn_i * 64;

    const int tid = threadIdx.x;
    const int wave = tid >> 6;
    const int lane = tid & 63;
    const int m16 = lane & 15;
    const int quad = lane >> 4;

    // ---- async stage whole B slice to LDS in fragment order ----
    {
        const f16* gs = Wt + (size_t)(bn + 16 * wave + m16) * K + quad * 8;
        #pragma unroll
        for (int j = 0; j < K32; ++j) {
            __builtin_amdgcn_global_load_lds(
                (gas_u32p)(const void*)(gs + j * 32),
                (las_u32p)(void*)(&Bs[((j * 4 + wave) * 64) * 8]),
                16, 0, 0);
        }
    }

    const int rb0 = bm + wave * 32;     // each wave owns 32 output rows
    int ar[2];
    #pragma unroll
    for (int mt = 0; mt < 2; ++mt) {
        int row = rb0 + mt * 16 + m16;
        ar[mt] = row < M ? row : M - 1;
    }

    // ---- prefetch this wave's ENTIRE A-slice into registers (one wait) ----
    f16x8 ahr[2][K32];
    #pragma unroll
    for (int mt = 0; mt < 2; ++mt) {
        const f16* ap = A + (size_t)ar[mt] * K + quad * 8;
        #pragma unroll
        for (int kc = 0; kc < K32; ++kc)
            ahr[mt][kc] = *(const f16x8*)(ap + kc * 32);
    }

    __syncthreads();   // drains global_load_lds (and A vmcnt)

    f32x4 acc[2][4];                    // [mt][nt]
    #pragma unroll
    for (int mt = 0; mt < 2; ++mt)
        #pragma unroll
        for (int nt = 0; nt < 4; ++nt) acc[mt][nt] = (f32x4){0.f, 0.f, 0.f, 0.f};

    // ---- K-loop: pure LDS + MFMA ----
    #pragma unroll
    for (int kc = 0; kc < K32; ++kc) {
        f16x8 bs[4];
        #pragma unroll
        for (int nt = 0; nt < 4; ++nt)
            bs[nt] = *(const f16x8*)&Bs[((kc * 4 + nt) * 64 + lane) * 8];
        #pragma unroll
        for (int nt = 0; nt < 4; ++nt)
            #pragma unroll
            for (int mt = 0; mt < 2; ++mt)
                acc[mt][nt] = __builtin_amdgcn_mfma_f32_16x16x32_f16(ahr[mt][kc], bs[nt], acc[mt][nt], 0, 0, 0);
    }

    __syncthreads();   // all waves done reading Bs -> safe to alias C staging onto it
    f16* Cs = Bs;

    // ---- epilogue (one 32-row half per wave) ----
    if (bn < b2) {
        f16* __restrict__ Fb;
        int cs, cb;
        if (bn >= b1) { Fb = F1; cb = bn - b1; cs = b2 - b1; }
        else          { Fb = F0; cb = bn;      cs = b1; }
        f16* cw = Cs + wave * (32 * 66);
        #pragma unroll
        for (int nt = 0; nt < 4; ++nt) {
            float bv = bias[bn + nt * 16 + m16];
            #pragma unroll
            for (int mt = 0; mt < 2; ++mt)
                #pragma unroll
                for (int r = 0; r < 4; ++r) {
                    int row = mt * 16 + quad * 4 + r;   // 0..31 within half
                    cw[row * 66 + nt * 16 + m16] = (f16)(acc[mt][nt][r] + bv);
                }
        }
        int lrow = lane >> 1;
        int lcol = (lane & 1) * 32;
        int grow = rb0 + lrow;
        if (grow < M) {
            #pragma unroll
            for (int j = 0; j < 4; ++j) {
                f16x8 v = *(f16x8*)&cw[lrow * 66 + lcol + j * 8];
                *(f16x8*)&Fb[(size_t)grow * cs + cb + lcol + j * 8] = v;
            }
        }
    } else {
        int cs = S - b2;
        #pragma unroll
        for (int nt = 0; nt < 4; ++nt) {
            int col = bn - b2 + nt * 16 + m16;
            float bv = bias[bn + nt * 16 + m16];
            #pragma unroll
            for (int mt = 0; mt < 2; ++mt)
                #pragma unroll
                for (int r = 0; r < 4; ++r) {
                    int row = rb0 + mt * 16 + quad * 4 + r;
                    if (row < M) F2[(size_t)row * cs + col] = acc[mt][nt][r] + bv;
                }
        }
    }
}

// ---------- fused GATv2 aggregate: 2 nodes per wave, 8 f16 dims per lane ----------
// csr region zeroed -> clamp-free. CSR indices ds_read from LDS. DPP group-sum
// (no bpermute/lgkm waits). exp2 with log2(e) folded into the f16 attn constants
// (exactly exp(p) -- softmax unchanged). Granularity-2 tail.
#define AGG_STEP(U0, CNT)                                                     \
    _Pragma("unroll")                                                         \
    for (int uu = 0; uu < (CNT); ++uu) {                                      \
        const int u = (U0) + uu;                                              \
        const f16x8 cur = buf[u];                                             \
        const unsigned su = (unsigned)cidx[u];                                \
        buf[u] = *(const f16x8*)&fsb[su * (unsigned)HD + off];                \
        cidx[u] = csr_l[nib64 + b + 16 + u];                                  \
        float pp = 0.f;                                                       \
        _Pragma("unroll")                                                     \
        for (int i = 0; i < 4; ++i) {                                         \
            f16x2 cp = (f16x2){cur[2 * i], cur[2 * i + 1]};                   \
            f16x2 xp = cp + fdp[i];                                           \
            unsigned xu = __builtin_bit_cast(unsigned, xp) & 0x7FFF7FFFu;     \
            f16x2 xa = __builtin_bit_cast(f16x2, xu);                         \
            pp = __builtin_amdgcn_fdot2(xp, a6p[i], pp, false);               \
            pp = __builtin_amdgcn_fdot2(xa, a4p[i], pp, false);               \
        }                                                                     \
        pp = group_sum<GSZ>(pp);                                              \
        float w = (b + u < dg) ? __builtin_amdgcn_exp2f(pp) : 0.f;            \
        lh += w;                                                              \
        _Pragma("unroll")                                                     \
        for (int d = 0; d < 8; ++d) acc[d] += w * (float)cur[d];              \
    }

template <int HD, int D, bool HAS_RES, bool DO_ELU, int OUT_MODE>
__global__ __launch_bounds__(256) void gat_node_aggregate(
        const f16* __restrict__ fsb, const f16* __restrict__ fdb,
        const float* __restrict__ attn,
        const unsigned int* __restrict__ degv,
        const int* __restrict__ csr_src,
        const float* __restrict__ resid, int RS,
        float* __restrict__ outF, f16* __restrict__ outA) {
    constexpr int LANES = HD / 8;   // active lanes per node (32 or 24)
    constexpr int GSZ = D / 8;      // lanes per head group (8 or 4)
    __shared__ int csr_l[544];      // 8 nodes x DEG_CAP + 32 zero pad
    __shared__ float red[(OUT_MODE == 2) ? 8 : 1][(OUT_MODE == 2) ? HD : 1];

    // ---- stage this block's CSR bucket slice (coalesced) + zero pad ----
    {
        int i = threadIdx.x;
        csr_l[i]       = csr_src[(size_t)blockIdx.x * 512 + i];
        csr_l[i + 256] = csr_src[(size_t)blockIdx.x * 512 + i + 256];
        if (i < 32) csr_l[512 + i] = 0;
    }

    const int wave = threadIdx.x >> 6;
    const int lane = threadIdx.x & 63;
    const int half = lane >> 5;            // 0 = node A, 1 = node B
    const int ln = lane & 31;              // lane within node
    const int t = blockIdx.x * 8 + wave * 2 + half;
    const bool active = (ln < LANES);
    const unsigned off = active ? 8u * ln : 0u;   // inactive lanes alias dims 0-7
    const int nib64 = (wave * 2 + half) * 64;

    f16x2 fdp[4], a6p[4], a4p[4];
    if (active) {
        f16x8 dv = *(const f16x8*)&fdb[(unsigned)t * HD + off];
        float4 aA = *(const float4*)&attn[off];
        float4 aB = *(const float4*)&attn[off + 4];
        float av[8] = {aA.x, aA.y, aA.z, aA.w, aB.x, aB.y, aB.z, aB.w};
        #pragma unroll
        for (int i = 0; i < 4; ++i) {
            fdp[i] = (f16x2){dv[2 * i], dv[2 * i + 1]};
            a6p[i] = (f16x2){(f16)(0.6f * LOG2E * av[2 * i]), (f16)(0.6f * LOG2E * av[2 * i + 1])};
            a4p[i] = (f16x2){(f16)(0.4f * LOG2E * av[2 * i]), (f16)(0.4f * LOG2E * av[2 * i + 1])};
        }
    } else {
        #pragma unroll
        for (int i = 0; i < 4; ++i) {
            fdp[i] = (f16x2){0, 0}; a6p[i] = (f16x2){0, 0}; a4p[i] = (f16x2){0, 0};
        }
    }

    const int dg = min((int)degv[t], DEG_CAP);
    const int degO = __shfl_xor(dg, 32, 64);
    const int mdeg = max(dg, degO);        // wave-uniform loop bound

    float acc[8];
    #pragma unroll
    for (int d = 0; d < 8; ++d) acc[d] = 0.f;
    float lh = 0.f;

    __syncthreads();   // csr_l ready

    // prologue: features for edges 0..7, indices for refill edges 8..15 (zeros beyond)
    f16x8 buf[8];
    int cidx[8];
    #pragma unroll
    for (int u = 0; u < 8; ++u) {
        unsigned s0 = (unsigned)csr_l[nib64 + u];
        buf[u] = *(const f16x8*)&fsb[s0 * (unsigned)HD + off];
        cidx[u] = csr_l[nib64 + 8 + u];
    }

    int b = 0;
    for (; b + 8 <= mdeg; b += 8) {
        AGG_STEP(0, 4)
        AGG_STEP(4, 4)
    }
    {
        const int rem = mdeg - b;
        if (rem > 0) { AGG_STEP(0, 2) }
        if (rem > 2) { AGG_STEP(2, 2) }
        if (rem > 4) { AGG_STEP(4, 2) }
        if (rem > 6) { AGG_STEP(6, 2) }
    }

    float inv = (lh > 0.f) ? 1.f / lh : 0.f;
    float vout[8];
    #pragma unroll
    for (int d = 0; d < 8; ++d) vout[d] = acc[d] * inv;
    if (HAS_RES && active) {
        float4 rA = *(const float4*)&resid[(unsigned)t * RS + off];
        float4 rB = *(const float4*)&resid[(unsigned)t * RS + off + 4];
        vout[0] += rA.x; vout[1] += rA.y; vout[2] += rA.z; vout[3] += rA.w;
        vout[4] += rB.x; vout[5] += rB.y; vout[6] += rB.z; vout[7] += rB.w;
    }
    if (DO_ELU) {
        #pragma unroll
        for (int d = 0; d < 8; ++d) vout[d] = vout[d] > 0.f ? vout[d] : expm1f(vout[d]);
    }

    if (OUT_MODE == 2) {
        const int nib = wave * 2 + half;
        if (active) {
            *(float4*)&red[nib][off] = make_float4(vout[0], vout[1], vout[2], vout[3]);
            *(float4*)&red[nib][off + 4] = make_float4(vout[4], vout[5], vout[6], vout[7]);
        }
        __syncthreads();
        // 8 nodes x 32 cols = 256 threads
        int node = threadIdx.x >> 5;
        int col = threadIdx.x & 31;
        float ssum = 0.f;
        #pragma unroll
        for (int h = 0; h < 6; ++h) ssum += red[node][h * 32 + col];
        outF[(unsigned)(blockIdx.x * 8 + node) * 32 + col] = ssum * (1.f / 6.f);
    } else if (active) {
        f16x8 av;
        #pragma unroll
        for (int d = 0; d < 8; ++d) av[d] = (f16)vout[d];
        *(f16x8*)&outA[(unsigned)t * HD + off] = av;
        if (OUT_MODE == 0) {
            *(float4*)&outF[(unsigned)t * HD + off] = make_float4(vout[0], vout[1], vout[2], vout[3]);
            *(float4*)&outF[(unsigned)t * HD + off + 4] = make_float4(vout[4], vout[5], vout[6], vout[7]);
        }
    }
}

extern "C" void kernel_launch(void* const* d_in, const int* in_sizes, int n_in,
                              void* d_out, int out_size, void* d_ws, size_t ws_size,
                              hipStream_t stream) {
    const float* x   = (const float*)d_in[0];
    const int*   src = (const int*)d_in[1];
    const int*   dst = (const int*)d_in[2];
    const float* W0s = (const float*)d_in[3];
    const float* b0s = (const float*)d_in[4];
    const float* W0d = (const float*)d_in[5];
    const float* b0d = (const float*)d_in[6];
    const float* a0  = (const float*)d_in[7];
    const float* W1s = (const float*)d_in[8];
    const float* b1s = (const float*)d_in[9];
    const float* W1d = (const float*)d_in[10];
    const float* b1d = (const float*)d_in[11];
    const float* a1  = (const float*)d_in[12];
    const float* W2s = (const float*)d_in[13];
    const float* b2s = (const float*)d_in[14];
    const float* W2d = (const float*)d_in[15];
    const float* b2d = (const float*)d_in[16];
    const float* a2  = (const float*)d_in[17];
    const float* Wr2 = (const float*)d_in[18];
    const float* br2 = (const float*)d_in[19];

    // ---- workspace layout ----
    f16* FsH = (f16*)d_ws;                           // N*256 f16 (fs, dense gather target)
    f16* FdH = FsH + (size_t)NN * 256;               // N*256 f16 (fd)
    f16* A   = FdH + (size_t)NN * 256;               // N*256 f16 (GEMM A input)
    float* O0 = (float*)(A + (size_t)NN * 256);      // N*256 fp32 (L1 residual; later L2 Fr N*192)
    f16* Wt0 = (f16*)(O0 + (size_t)NN * 256);        // 512*128
    f16* Wt1 = Wt0 + 512 * 128;                      // 512*256
    f16* Wt2 = Wt1 + 512 * 256;                      // 576*256
    float* bias0 = (float*)(Wt2 + 576 * 256);        // 512
    float* bias1 = bias0 + 512;                      // 512
    float* bias2 = bias1 + 512;                      // 576
    unsigned int* deg = (unsigned int*)(bias2 + 576);      // N counts (doubles as cursor)
    int* csr_src      = (int*)(deg + NN);                  // N * DEG_CAP bucketed (zeroed)

    // ---- zero deg + csr buckets (one contiguous memset; clamp-free aggregate) ----
    hipMemsetAsync(deg, 0, (size_t)NN * 4 + (size_t)NN * DEG_CAP * 4, stream);
    {
        int total = SEG0 + SEG1 + SEG2 + SEG3;
        prep_all<<<(total + 255) / 256, 256, 0, stream>>>(
            W0s, b0s, W0d, b0d, W1s, b1s, W1d, b1d, W2s, b2s, W2d, b2d, Wr2, br2, x,
            Wt0, bias0, Wt1, bias1, Wt2, bias2, A);
    }

    const int gy = (NN + 127) / 128;           // 157 bm tiles (BM=128)
    const int gy8 = ((gy + 7) / 8) * 8;        // 160 (rounded for swizzle)
    const int nagg = NN / 8;                   // 2500 blocks, 8 nodes each (2 per wave)
    const int sblk = (EE + 255) / 256;         // scatter blocks folded into gemm0 (FIRST)

    // ---- layer 0: scatter blocks + GEMM<K=128> -> aggregate ----
    gemm_mfma_f16<128><<<sblk + gy8 * 8, 256, 0, stream>>>(A, Wt0, bias0,
                                               FsH, FdH, nullptr, 256, 512, NN, 512, 8, gy,
                                               sblk, src, dst, deg, csr_src, EE);
    gat_node_aggregate<256, 64, false, true, 0><<<nagg, 256, 0, stream>>>(
        FsH, FdH, a0, deg, csr_src, nullptr, 0, O0, A);

    // ---- layer 1: GEMM<K=256> ----
    gemm_mfma_f16<256><<<gy8 * 8, 256, 0, stream>>>(A, Wt1, bias1,
                                               FsH, FdH, nullptr, 256, 512, NN, 512, 8, gy,
                                               0, nullptr, nullptr, nullptr, nullptr, 0);
    gat_node_aggregate<256, 64, true, true, 1><<<nagg, 256, 0, stream>>>(
        FsH, FdH, a1, deg, csr_src, O0, 256, nullptr, A);

    // ---- layer 2: GEMM<K=256> ----
    gemm_mfma_f16<256><<<gy8 * 9, 256, 0, stream>>>(A, Wt2, bias2,
                                               FsH, FdH, O0, 192, 384, NN, 576, 9, gy,
                                               0, nullptr, nullptr, nullptr, nullptr, 0);
    gat_node_aggregate<192, 32, true, false, 2><<<nagg, 256, 0, stream>>>(
        FsH, FdH, a2, deg, csr_src, O0, 192, (float*)d_out, nullptr);
}

// Round 12
// 252.649 us; speedup vs baseline: 1.0655x; 1.0655x over previous
//
#include <hip/hip_runtime.h>
#include <hip/hip_bf16.h>
#include <float.h>
#include <math.h>

// Problem constants (from reference)
#define NN 20000
#define EE 320000
#define IN_DIM 128
#define DEG_CAP 64   // bucket stride; Poisson(16) => P(max deg > 64) ~ 1e-13

typedef __attribute__((ext_vector_type(4))) float f32x4;
typedef _Float16 f16;
typedef __attribute__((ext_vector_type(2))) _Float16 f16x2;
typedef __attribute__((ext_vector_type(4))) _Float16 f16x4;
typedef __attribute__((ext_vector_type(8))) _Float16 f16x8;

#define LOG2E 1.4426950408889634f

// DPP lane-group sum stage: v += dpp(v, CTRL). Pure VALU (no LDS/bpermute).
template <int CTRL>
__device__ __forceinline__ float dpp_add(float v) {
    int x = __builtin_amdgcn_update_dpp(0, __builtin_bit_cast(int, v), CTRL, 0xF, 0xF, false);
    return v + __builtin_bit_cast(float, x);
}
// Complete sum over aligned lane group of GSZ (8: half-mirror+xor1+xor2; 4: xor1+xor2).
template <int GSZ>
__device__ __forceinline__ float group_sum(float v) {
    if constexpr (GSZ == 8) v = dpp_add<0x141>(v);   // row_half_mirror: i <-> 7-i
    v = dpp_add<0xB1>(v);                             // quad_perm [1,0,3,2]: xor 1
    v = dpp_add<0x4E>(v);                             // quad_perm [2,3,0,1]: xor 2
    return v;
}

// ---------- fused MFMA GEMM: in-kernel weight transpose (prep kernel DELETED) ----------
// B-slice read straight from W f32 [K x ncols] (coalesced 256B row-reads, lane=col,
// wave=k-octet), RNE-cast to f16 (identical to old prep cast), one ds_write_b128/pass
// into the exact fragment layout: chunk = (pass*4 + (lane>>4))*64 + wave*16 + (lane&15).
// AF32: layer-0 reads A from x f32 and converts at prefetch (bit-identical to old SEG3).
// Scatter blocks FIRST (bid < SB) build the bucketed CSR (layer-0 launch only).
template <int K, bool AF32>
__global__ __launch_bounds__(256) void gemm_fused(
        const void* __restrict__ Av,
        const float* __restrict__ Wa, const float* __restrict__ ba, int na,
        const float* __restrict__ Wb, const float* __restrict__ bb, int nb,
        const float* __restrict__ Wc, const float* __restrict__ bc,
        f16* __restrict__ F0, f16* __restrict__ F1, float* __restrict__ F2,
        int b1, int b2, int M, int S, int gx, int gy,
        int SB, const int* __restrict__ esrc, const int* __restrict__ edst,
        unsigned int* __restrict__ cursor, int* __restrict__ csr_dst, int E) {
    constexpr int K32 = K / 32;
    constexpr int BSN = (64 * K > 4 * 32 * 66) ? 64 * K : 4 * 32 * 66;
    __shared__ f16 Bs[BSN];          // K=256: 32KB; K=128: 16.9KB

    if (blockIdx.x < (unsigned)SB) {
        // ---- CSR bucket scatter segment (runs FIRST; overlaps the GEMM) ----
        int e = blockIdx.x * 256 + threadIdx.x;
        if (e < E) {
            int d = edst[e];
            unsigned pos = atomicAdd(&cursor[d], 1u);
            if (pos < DEG_CAP) csr_dst[(unsigned)d * DEG_CAP + pos] = esrc[e];
        }
        return;
    }
    const int bid = blockIdx.x - SB;

    const int p = bid & 7;          // XCD slot
    const int q = bid >> 3;
    const int bn_i = q % gx;
    const int bm_i = (q / gx) * 8 + p;
    if (bm_i >= gy) return;
    const int bm = bm_i * 128;
    const int bn = bn_i * 64;

    const int tid = threadIdx.x;
    const int wave = tid >> 6;
    const int lane = tid & 63;
    const int m16 = lane & 15;
    const int quad = lane >> 4;

    // ---- region select (tile boundaries are 64-multiples: never straddle) ----
    const float* Wsrc; const float* bsrc; int ncols, cbl;
    if (bn < na)           { Wsrc = Wa; bsrc = ba; ncols = na;           cbl = bn; }
    else if (bn < na + nb) { Wsrc = Wb; bsrc = bb; ncols = nb;           cbl = bn - na; }
    else                   { Wsrc = Wc; bsrc = bc; ncols = S - na - nb;  cbl = bn - na - nb; }

    // ---- in-kernel transpose stage: W f32 col-slice -> Bs fragment order ----
    {
        #pragma unroll
        for (int pass = 0; pass < K32; ++pass) {
            const int k0 = pass * 32 + wave * 8;          // this wave's k-octet
            const float* wp = Wsrc + (size_t)k0 * ncols + cbl + lane;
            float v[8];
            #pragma unroll
            for (int j = 0; j < 8; ++j) v[j] = wp[(size_t)j * ncols];
            f16x8 h;
            #pragma unroll
            for (int j = 0; j < 8; ++j) h[j] = (f16)v[j];   // RNE, same as old prep
            int chunk = (pass * 4 + (lane >> 4)) * 64 + wave * 16 + (lane & 15);
            *(f16x8*)&Bs[chunk * 8] = h;
        }
    }

    const int rb0 = bm + wave * 32;     // each wave owns 32 output rows
    int ar[2];
    #pragma unroll
    for (int mt = 0; mt < 2; ++mt) {
        int row = rb0 + mt * 16 + m16;
        ar[mt] = row < M ? row : M - 1;
    }

    // ---- prefetch this wave's ENTIRE A-slice into registers (one wait) ----
    f16x8 ahr[2][K32];
    #pragma unroll
    for (int mt = 0; mt < 2; ++mt) {
        if constexpr (AF32) {
            const float* ap = (const float*)Av + (size_t)ar[mt] * K + quad * 8;
            #pragma unroll
            for (int kc = 0; kc < K32; ++kc) {
                float4 u = *(const float4*)(ap + kc * 32);
                float4 w = *(const float4*)(ap + kc * 32 + 4);
                ahr[mt][kc] = (f16x8){(f16)u.x, (f16)u.y, (f16)u.z, (f16)u.w,
                                      (f16)w.x, (f16)w.y, (f16)w.z, (f16)w.w};
            }
        } else {
            const f16* ap = (const f16*)Av + (size_t)ar[mt] * K + quad * 8;
            #pragma unroll
            for (int kc = 0; kc < K32; ++kc)
                ahr[mt][kc] = *(const f16x8*)(ap + kc * 32);
        }
    }

    __syncthreads();   // Bs writes visible to all waves

    f32x4 acc[2][4];                    // [mt][nt]
    #pragma unroll
    for (int mt = 0; mt < 2; ++mt)
        #pragma unroll
        for (int nt = 0; nt < 4; ++nt) acc[mt][nt] = (f32x4){0.f, 0.f, 0.f, 0.f};

    // ---- K-loop: pure LDS + MFMA ----
    #pragma unroll
    for (int kc = 0; kc < K32; ++kc) {
        f16x8 bs[4];
        #pragma unroll
        for (int nt = 0; nt < 4; ++nt)
            bs[nt] = *(const f16x8*)&Bs[((kc * 4 + nt) * 64 + lane) * 8];
        #pragma unroll
        for (int nt = 0; nt < 4; ++nt)
            #pragma unroll
            for (int mt = 0; mt < 2; ++mt)
                acc[mt][nt] = __builtin_amdgcn_mfma_f32_16x16x32_f16(ahr[mt][kc], bs[nt], acc[mt][nt], 0, 0, 0);
    }

    __syncthreads();   // all waves done reading Bs -> safe to alias C staging onto it
    f16* Cs = Bs;

    // ---- epilogue (one 32-row half per wave) ----
    if (bn < b2) {
        f16* __restrict__ Fb;
        int cs, cb;
        if (bn >= b1) { Fb = F1; cb = bn - b1; cs = b2 - b1; }
        else          { Fb = F0; cb = bn;      cs = b1; }
        f16* cw = Cs + wave * (32 * 66);
        #pragma unroll
        for (int nt = 0; nt < 4; ++nt) {
            float bv = bsrc[cbl + nt * 16 + m16];
            #pragma unroll
            for (int mt = 0; mt < 2; ++mt)
                #pragma unroll
                for (int r = 0; r < 4; ++r) {
                    int row = mt * 16 + quad * 4 + r;   // 0..31 within half
                    cw[row * 66 + nt * 16 + m16] = (f16)(acc[mt][nt][r] + bv);
                }
        }
        int lrow = lane >> 1;
        int lcol = (lane & 1) * 32;
        int grow = rb0 + lrow;
        if (grow < M) {
            #pragma unroll
            for (int j = 0; j < 4; ++j) {
                f16x8 v = *(f16x8*)&cw[lrow * 66 + lcol + j * 8];
                *(f16x8*)&Fb[(size_t)grow * cs + cb + lcol + j * 8] = v;
            }
        }
    } else {
        int cs = S - b2;
        #pragma unroll
        for (int nt = 0; nt < 4; ++nt) {
            int col = bn - b2 + nt * 16 + m16;
            float bv = bsrc[cbl + nt * 16 + m16];
            #pragma unroll
            for (int mt = 0; mt < 2; ++mt)
                #pragma unroll
                for (int r = 0; r < 4; ++r) {
                    int row = rb0 + mt * 16 + quad * 4 + r;
                    if (row < M) F2[(size_t)row * cs + col] = acc[mt][nt][r] + bv;
                }
        }
    }
}

// ---------- fused GATv2 aggregate: 2 nodes per wave, 8 f16 dims per lane ----------
// csr region zeroed -> clamp-free. CSR indices ds_read from LDS. DPP group-sum.
// exp2 with log2(e) folded into the f16 attn constants (exactly exp(p)).
#define AGG_STEP(U0, CNT)                                                     \
    _Pragma("unroll")                                                         \
    for (int uu = 0; uu < (CNT); ++uu) {                                      \
        const int u = (U0) + uu;                                              \
        const f16x8 cur = buf[u];                                             \
        const unsigned su = (unsigned)cidx[u];                                \
        buf[u] = *(const f16x8*)&fsb[su * (unsigned)HD + off];                \
        cidx[u] = csr_l[nib64 + b + 16 + u];                                  \
        float pp = 0.f;                                                       \
        _Pragma("unroll")                                                     \
        for (int i = 0; i < 4; ++i) {                                         \
            f16x2 cp = (f16x2){cur[2 * i], cur[2 * i + 1]};                   \
            f16x2 xp = cp + fdp[i];                                           \
            unsigned xu = __builtin_bit_cast(unsigned, xp) & 0x7FFF7FFFu;     \
            f16x2 xa = __builtin_bit_cast(f16x2, xu);                         \
            pp = __builtin_amdgcn_fdot2(xp, a6p[i], pp, false);               \
            pp = __builtin_amdgcn_fdot2(xa, a4p[i], pp, false);               \
        }                                                                     \
        pp = group_sum<GSZ>(pp);                                              \
        float w = (b + u < dg) ? __builtin_amdgcn_exp2f(pp) : 0.f;            \
        lh += w;                                                              \
        _Pragma("unroll")                                                     \
        for (int d = 0; d < 8; ++d) acc[d] += w * (float)cur[d];              \
    }

template <int HD, int D, bool HAS_RES, bool DO_ELU, int OUT_MODE>
__global__ __launch_bounds__(256) void gat_node_aggregate(
        const f16* __restrict__ fsb, const f16* __restrict__ fdb,
        const float* __restrict__ attn,
        const unsigned int* __restrict__ degv,
        const int* __restrict__ csr_src,
        const float* __restrict__ resid, int RS,
        float* __restrict__ outF, f16* __restrict__ outA) {
    constexpr int LANES = HD / 8;   // active lanes per node (32 or 24)
    constexpr int GSZ = D / 8;      // lanes per head group (8 or 4)
    __shared__ int csr_l[544];      // 8 nodes x DEG_CAP + 32 zero pad
    __shared__ float red[(OUT_MODE == 2) ? 8 : 1][(OUT_MODE == 2) ? HD : 1];

    // ---- stage this block's CSR bucket slice (coalesced) + zero pad ----
    {
        int i = threadIdx.x;
        csr_l[i]       = csr_src[(size_t)blockIdx.x * 512 + i];
        csr_l[i + 256] = csr_src[(size_t)blockIdx.x * 512 + i + 256];
        if (i < 32) csr_l[512 + i] = 0;
    }

    const int wave = threadIdx.x >> 6;
    const int lane = threadIdx.x & 63;
    const int half = lane >> 5;            // 0 = node A, 1 = node B
    const int ln = lane & 31;              // lane within node
    const int t = blockIdx.x * 8 + wave * 2 + half;
    const bool active = (ln < LANES);
    const unsigned off = active ? 8u * ln : 0u;   // inactive lanes alias dims 0-7
    const int nib64 = (wave * 2 + half) * 64;

    f16x2 fdp[4], a6p[4], a4p[4];
    if (active) {
        f16x8 dv = *(const f16x8*)&fdb[(unsigned)t * HD + off];
        float4 aA = *(const float4*)&attn[off];
        float4 aB = *(const float4*)&attn[off + 4];
        float av[8] = {aA.x, aA.y, aA.z, aA.w, aB.x, aB.y, aB.z, aB.w};
        #pragma unroll
        for (int i = 0; i < 4; ++i) {
            fdp[i] = (f16x2){dv[2 * i], dv[2 * i + 1]};
            a6p[i] = (f16x2){(f16)(0.6f * LOG2E * av[2 * i]), (f16)(0.6f * LOG2E * av[2 * i + 1])};
            a4p[i] = (f16x2){(f16)(0.4f * LOG2E * av[2 * i]), (f16)(0.4f * LOG2E * av[2 * i + 1])};
        }
    } else {
        #pragma unroll
        for (int i = 0; i < 4; ++i) {
            fdp[i] = (f16x2){0, 0}; a6p[i] = (f16x2){0, 0}; a4p[i] = (f16x2){0, 0};
        }
    }

    const int dg = min((int)degv[t], DEG_CAP);
    const int degO = __shfl_xor(dg, 32, 64);
    const int mdeg = max(dg, degO);        // wave-uniform loop bound

    float acc[8];
    #pragma unroll
    for (int d = 0; d < 8; ++d) acc[d] = 0.f;
    float lh = 0.f;

    __syncthreads();   // csr_l ready

    // prologue: features for edges 0..7, indices for refill edges 8..15 (zeros beyond)
    f16x8 buf[8];
    int cidx[8];
    #pragma unroll
    for (int u = 0; u < 8; ++u) {
        unsigned s0 = (unsigned)csr_l[nib64 + u];
        buf[u] = *(const f16x8*)&fsb[s0 * (unsigned)HD + off];
        cidx[u] = csr_l[nib64 + 8 + u];
    }

    int b = 0;
    for (; b + 8 <= mdeg; b += 8) {
        AGG_STEP(0, 4)
        AGG_STEP(4, 4)
    }
    {
        const int rem = mdeg - b;
        if (rem > 0) { AGG_STEP(0, 2) }
        if (rem > 2) { AGG_STEP(2, 2) }
        if (rem > 4) { AGG_STEP(4, 2) }
        if (rem > 6) { AGG_STEP(6, 2) }
    }

    float inv = (lh > 0.f) ? 1.f / lh : 0.f;
    float vout[8];
    #pragma unroll
    for (int d = 0; d < 8; ++d) vout[d] = acc[d] * inv;
    if (HAS_RES && active) {
        float4 rA = *(const float4*)&resid[(unsigned)t * RS + off];
        float4 rB = *(const float4*)&resid[(unsigned)t * RS + off + 4];
        vout[0] += rA.x; vout[1] += rA.y; vout[2] += rA.z; vout[3] += rA.w;
        vout[4] += rB.x; vout[5] += rB.y; vout[6] += rB.z; vout[7] += rB.w;
    }
    if (DO_ELU) {
        #pragma unroll
        for (int d = 0; d < 8; ++d) vout[d] = vout[d] > 0.f ? vout[d] : expm1f(vout[d]);
    }

    if (OUT_MODE == 2) {
        const int nib = wave * 2 + half;
        if (active) {
            *(float4*)&red[nib][off] = make_float4(vout[0], vout[1], vout[2], vout[3]);
            *(float4*)&red[nib][off + 4] = make_float4(vout[4], vout[5], vout[6], vout[7]);
        }
        __syncthreads();
        // 8 nodes x 32 cols = 256 threads
        int node = threadIdx.x >> 5;
        int col = threadIdx.x & 31;
        float ssum = 0.f;
        #pragma unroll
        for (int h = 0; h < 6; ++h) ssum += red[node][h * 32 + col];
        outF[(unsigned)(blockIdx.x * 8 + node) * 32 + col] = ssum * (1.f / 6.f);
    } else if (active) {
        f16x8 av;
        #pragma unroll
        for (int d = 0; d < 8; ++d) av[d] = (f16)vout[d];
        *(f16x8*)&outA[(unsigned)t * HD + off] = av;
        if (OUT_MODE == 0) {
            *(float4*)&outF[(unsigned)t * HD + off] = make_float4(vout[0], vout[1], vout[2], vout[3]);
            *(float4*)&outF[(unsigned)t * HD + off + 4] = make_float4(vout[4], vout[5], vout[6], vout[7]);
        }
    }
}

extern "C" void kernel_launch(void* const* d_in, const int* in_sizes, int n_in,
                              void* d_out, int out_size, void* d_ws, size_t ws_size,
                              hipStream_t stream) {
    const float* x   = (const float*)d_in[0];
    const int*   src = (const int*)d_in[1];
    const int*   dst = (const int*)d_in[2];
    const float* W0s = (const float*)d_in[3];
    const float* b0s = (const float*)d_in[4];
    const float* W0d = (const float*)d_in[5];
    const float* b0d = (const float*)d_in[6];
    const float* a0  = (const float*)d_in[7];
    const float* W1s = (const float*)d_in[8];
    const float* b1s = (const float*)d_in[9];
    const float* W1d = (const float*)d_in[10];
    const float* b1d = (const float*)d_in[11];
    const float* a1  = (const float*)d_in[12];
    const float* W2s = (const float*)d_in[13];
    const float* b2s = (const float*)d_in[14];
    const float* W2d = (const float*)d_in[15];
    const float* b2d = (const float*)d_in[16];
    const float* a2  = (const float*)d_in[17];
    const float* Wr2 = (const float*)d_in[18];
    const float* br2 = (const float*)d_in[19];

    // ---- workspace layout ----
    f16* FsH = (f16*)d_ws;                           // N*256 f16 (fs, dense gather target)
    f16* FdH = FsH + (size_t)NN * 256;               // N*256 f16 (fd)
    f16* A   = FdH + (size_t)NN * 256;               // N*256 f16 (layer 1/2 GEMM input)
    float* O0 = (float*)(A + (size_t)NN * 256);      // N*256 fp32 (L1 residual; later L2 Fr N*192)
    unsigned int* deg = (unsigned int*)(O0 + (size_t)NN * 256);  // N counts (doubles as cursor)
    int* csr_src      = (int*)(deg + NN);                        // N * DEG_CAP bucketed (zeroed)

    // ---- zero deg + csr buckets (one contiguous memset; clamp-free aggregate) ----
    hipMemsetAsync(deg, 0, (size_t)NN * 4 + (size_t)NN * DEG_CAP * 4, stream);

    const int gy = (NN + 127) / 128;           // 157 bm tiles (BM=128)
    const int gy8 = ((gy + 7) / 8) * 8;        // 160 (rounded for swizzle)
    const int nagg = NN / 8;                   // 2500 blocks, 8 nodes each (2 per wave)
    const int sblk = (EE + 255) / 256;         // scatter blocks folded into gemm0 (FIRST)

    // ---- layer 0: scatter + GEMM<K=128, A=f32 x> (in-kernel W transpose) -> aggregate ----
    gemm_fused<128, true><<<sblk + gy8 * 8, 256, 0, stream>>>(
        x, W0s, b0s, 256, W0d, b0d, 256, nullptr, nullptr,
        FsH, FdH, nullptr, 256, 512, NN, 512, 8, gy,
        sblk, src, dst, deg, csr_src, EE);
    gat_node_aggregate<256, 64, false, true, 0><<<nagg, 256, 0, stream>>>(
        FsH, FdH, a0, deg, csr_src, nullptr, 0, O0, A);

    // ---- layer 1: GEMM<K=256, A=f16> ----
    gemm_fused<256, false><<<gy8 * 8, 256, 0, stream>>>(
        A, W1s, b1s, 256, W1d, b1d, 256, nullptr, nullptr,
        FsH, FdH, nullptr, 256, 512, NN, 512, 8, gy,
        0, nullptr, nullptr, nullptr, nullptr, 0);
    gat_node_aggregate<256, 64, true, true, 1><<<nagg, 256, 0, stream>>>(
        FsH, FdH, a1, deg, csr_src, O0, 256, nullptr, A);

    // ---- layer 2: GEMM<K=256, A=f16> (3-way concat: W2s|W2d|Wr2) ----
    gemm_fused<256, false><<<gy8 * 9, 256, 0, stream>>>(
        A, W2s, b2s, 192, W2d, b2d, 192, Wr2, br2,
        FsH, FdH, O0, 192, 384, NN, 576, 9, gy,
        0, nullptr, nullptr, nullptr, nullptr, 0);
    gat_node_aggregate<192, 32, true, false, 2><<<nagg, 256, 0, stream>>>(
        FsH, FdH, a2, deg, csr_src, O0, 192, (float*)d_out, nullptr);
}